// Round 7
// baseline (568.526 us; speedup 1.0000x reference)
//
#include <hip/hip_runtime.h>
#include <hip/hip_bf16.h>

#define NN 100000
#define EE 800000
#define MPAD 100096   // 782*128 = 1564*64 = 391*256
#define MT64 1564
#define MT128 782

typedef __attribute__((ext_vector_type(4))) float f32x4;
typedef __attribute__((ext_vector_type(8))) short s16x8;

__device__ __forceinline__ float bfu(unsigned short u) {
    union { unsigned i; float f; } x; x.i = ((unsigned)u) << 16; return x.f;
}
__device__ __forceinline__ unsigned short fbf(float f) {
    union { float f; unsigned i; } x; x.f = f;
    unsigned r = x.i + (((x.i >> 16) & 1u) + 0x7fffu);  // RNE
    return (unsigned short)(r >> 16);
}
__device__ __forceinline__ uint4 pack8(const float* a) {
    uint4 o;
    o.x = (unsigned)fbf(a[0]) | ((unsigned)fbf(a[1]) << 16);
    o.y = (unsigned)fbf(a[2]) | ((unsigned)fbf(a[3]) << 16);
    o.z = (unsigned)fbf(a[4]) | ((unsigned)fbf(a[5]) << 16);
    o.w = (unsigned)fbf(a[6]) | ((unsigned)fbf(a[7]) << 16);
    return o;
}
__device__ __forceinline__ void acc8(float* a, uint4 v) {
    a[0] += bfu((unsigned short)v.x); a[1] += bfu((unsigned short)(v.x >> 16));
    a[2] += bfu((unsigned short)v.y); a[3] += bfu((unsigned short)(v.y >> 16));
    a[4] += bfu((unsigned short)v.z); a[5] += bfu((unsigned short)(v.z >> 16));
    a[6] += bfu((unsigned short)v.w); a[7] += bfu((unsigned short)(v.w >> 16));
}
__device__ __forceinline__ void load_lds16(const void* g, void* l) {
    __builtin_amdgcn_global_load_lds((const __attribute__((address_space(1))) void*)g,
                                     (__attribute__((address_space(3))) void*)l, 16, 0, 0);
}

// ---------------- graph prep ----------------

__global__ void hist_k(const int* __restrict__ ei, int* __restrict__ counts) {
    int e = blockIdx.x * 256 + threadIdx.x;
    if (e < EE) atomicAdd(&counts[ei[EE + e]], 1);
}

__global__ void scan1_k(const int* __restrict__ counts, int* __restrict__ rp, int* __restrict__ bsum) {
    __shared__ int lds[256];
    int b = blockIdx.x, t = threadIdx.x;
    int base = b * 1024 + t * 4;
    int v[4]; int s = 0;
#pragma unroll
    for (int j = 0; j < 4; ++j) { v[j] = (base + j < NN) ? counts[base + j] : 0; s += v[j]; }
    lds[t] = s; __syncthreads();
    for (int off = 1; off < 256; off <<= 1) {
        int x = (t >= off) ? lds[t - off] : 0;
        __syncthreads();
        lds[t] += x;
        __syncthreads();
    }
    int run = lds[t] - s;
    if (t == 255) bsum[b] = lds[255];
#pragma unroll
    for (int j = 0; j < 4; ++j) { if (base + j < NN) rp[base + j] = run; run += v[j]; }
}

// one-wave shuffle prefix over nb<=128 block sums
__global__ void scan2_k(int* __restrict__ bsum, int nb) {
    int l = threadIdx.x;
    int v0 = (l < nb) ? bsum[l] : 0;
    int v1 = (64 + l < nb) ? bsum[64 + l] : 0;
    int s0 = v0, s1 = v1;
    for (int off = 1; off < 64; off <<= 1) {
        int t0 = __shfl_up(s0, off); if (l >= off) s0 += t0;
        int t1 = __shfl_up(s1, off); if (l >= off) s1 += t1;
    }
    int tot0 = __shfl(s0, 63);
    if (l < nb) bsum[l] = s0 - v0;
    if (64 + l < nb) bsum[64 + l] = tot0 + s1 - v1;
}

// finalize row_ptr, make fill copy (into counts), dinv = rsqrt(deg+1)
__global__ void scan3_k(int* __restrict__ rp, const int* __restrict__ bsum,
                        int* __restrict__ counts, float* __restrict__ dinv) {
    int i = blockIdx.x * 256 + threadIdx.x;
    if (i == 0) rp[NN] = EE;
    if (i < NN) {
        int v = rp[i] + bsum[i >> 10];
        int deg = counts[i];
        rp[i] = v;
        counts[i] = v;  // fill cursor
        dinv[i] = rsqrtf((float)deg + 1.0f);
    }
}

__global__ void fill_k(const int* __restrict__ ei, int* __restrict__ fill, int* __restrict__ esrc) {
    int e = blockIdx.x * 256 + threadIdx.x;
    if (e < EE) {
        int d = ei[EE + e];
        int slot = atomicAdd(&fill[d], 1);
        esrc[slot] = ei[e];
    }
}

// ---------------- conversions ----------------

__global__ void xcvt_k(const float* __restrict__ x, __hip_bfloat16* __restrict__ A1) {
    int idx = blockIdx.x * 256 + threadIdx.x;
    if (idx < NN * 32) {
        int row = idx >> 5; int c4 = (idx & 31) * 4;
        float4 v = *(const float4*)(x + (size_t)row * 128 + c4);
        ushort4 o; o.x = fbf(v.x); o.y = fbf(v.y); o.z = fbf(v.z); o.w = fbf(v.w);
        *(ushort4*)((unsigned short*)A1 + (size_t)row * 256 + 128 + c4) = o;
    }
}

__global__ void wprep_k(const float* __restrict__ W1l, const float* __restrict__ W1r,
                        const float* __restrict__ W2l, const float* __restrict__ W2r,
                        const float* __restrict__ Wr,  const float* __restrict__ Wmu,
                        const float* __restrict__ Wls,
                        unsigned short* __restrict__ B1T, unsigned short* __restrict__ B2T,
                        unsigned short* __restrict__ B3T) {
    int idx = blockIdx.x * 256 + threadIdx.x;
    if (idx < 65536) {                         // B1T [256n][256k]
        int n = idx >> 8, k = idx & 255;
        float v = (k < 128) ? W1l[k * 256 + n] : W1r[(k - 128) * 256 + n];
        B1T[idx] = fbf(v);
    } else if (idx < 229376) {                 // B2T [256n][640k]
        int j = idx - 65536;
        int n = j / 640, k = j - n * 640;
        float v = (k < 256) ? W2l[k * 256 + n]
                : (k < 512) ? W2r[(k - 256) * 256 + n]
                            : Wr[(k - 512) * 256 + n];
        B2T[j] = fbf(v);
    } else if (idx < 262144) {                 // B3T [128n][256k]
        int j = idx - 229376;
        int n = j >> 8, k = j & 255;
        float v = (n < 64) ? Wmu[k * 64 + n] : Wls[k * 64 + (n - 64)];
        B3T[j] = fbf(v);
    }
}

// ---------------- aggregations (wave per node, multi-edge subgroups, 2x unroll) ----------------

// agg1: mean of x rows (128 cols bf16): 4 subgroups x 16 lanes, unroll 2 -> 8 rows in flight/wave
__global__ __launch_bounds__(256) void agg1_k(const int* __restrict__ rp, const int* __restrict__ esrc,
                                              __hip_bfloat16* __restrict__ A1) {
    int wid = threadIdx.x >> 6, lane = threadIdx.x & 63;
    int node = blockIdx.x * 4 + wid;
    if (node >= NN) return;
    int e0 = rp[node], e1 = rp[node + 1];
    int sg = lane >> 4, lc = lane & 15;
    const unsigned short* X = (const unsigned short*)A1;
    float a[8] = {}, b[8] = {};
    int e = e0 + sg;
    for (; e + 4 < e1; e += 8) {
        int s0 = esrc[e], s1 = esrc[e + 4];
        uint4 v0 = *(const uint4*)(X + (size_t)s0 * 256 + 128 + lc * 8);
        uint4 v1 = *(const uint4*)(X + (size_t)s1 * 256 + 128 + lc * 8);
        acc8(a, v0); acc8(b, v1);
    }
    if (e < e1) {
        uint4 v = *(const uint4*)(X + (size_t)esrc[e] * 256 + 128 + lc * 8);
        acc8(a, v);
    }
#pragma unroll
    for (int k = 0; k < 8; ++k) {
        a[k] += b[k];
        a[k] += __shfl_xor(a[k], 16);
        a[k] += __shfl_xor(a[k], 32);
    }
    int deg = e1 - e0;
    float sc = 1.0f / (float)(deg > 1 ? deg : 1);
    if (lane < 16) {
#pragma unroll
        for (int k = 0; k < 8; ++k) a[k] *= sc;
        *(uint4*)((unsigned short*)A1 + (size_t)node * 256 + lane * 8) = pack8(a);
    }
}

// agg2: mean of h1 rows (256 cols bf16): 2 subgroups x 32 lanes, unroll 2 -> 4 rows in flight/wave
__global__ __launch_bounds__(256) void agg2_k(const int* __restrict__ rp, const int* __restrict__ esrc,
                                              const __hip_bfloat16* __restrict__ H1,
                                              __hip_bfloat16* __restrict__ AGG2) {
    int wid = threadIdx.x >> 6, lane = threadIdx.x & 63;
    int node = blockIdx.x * 4 + wid;
    if (node >= NN) return;
    int e0 = rp[node], e1 = rp[node + 1];
    int sg = lane >> 5, lc = lane & 31;
    const unsigned short* H = (const unsigned short*)H1;
    float a[8] = {}, b[8] = {};
    int e = e0 + sg;
    for (; e + 2 < e1; e += 4) {
        int s0 = esrc[e], s1 = esrc[e + 2];
        uint4 v0 = *(const uint4*)(H + (size_t)s0 * 256 + lc * 8);
        uint4 v1 = *(const uint4*)(H + (size_t)s1 * 256 + lc * 8);
        acc8(a, v0); acc8(b, v1);
    }
    if (e < e1) {
        uint4 v = *(const uint4*)(H + (size_t)esrc[e] * 256 + lc * 8);
        acc8(a, v);
    }
#pragma unroll
    for (int k = 0; k < 8; ++k) {
        a[k] += b[k];
        a[k] += __shfl_xor(a[k], 32);
    }
    int deg = e1 - e0;
    float sc = 1.0f / (float)(deg > 1 ? deg : 1);
    if (lane < 32) {
#pragma unroll
        for (int k = 0; k < 8; ++k) a[k] *= sc;
        *(uint4*)((unsigned short*)AGG2 + (size_t)node * 256 + lane * 8) = pack8(a);
    }
}

// gcn agg: out_i = dinv_i * (xws_i + sum_e xws[src_e]) + bias; XWS rows 128 cols bf16
__global__ __launch_bounds__(256) void gcnagg_k(const int* __restrict__ rp, const int* __restrict__ esrc,
                                                const __hip_bfloat16* __restrict__ XWS,
                                                const float* __restrict__ dinv,
                                                const float* __restrict__ bmu, const float* __restrict__ bls,
                                                float* __restrict__ out) {
    int wid = threadIdx.x >> 6, lane = threadIdx.x & 63;
    int node = blockIdx.x * 4 + wid;
    if (node >= NN) return;
    int e0 = rp[node], e1 = rp[node + 1];
    int sg = lane >> 4, lc = lane & 15;
    const unsigned short* W = (const unsigned short*)XWS;
    float a[8] = {}, b[8] = {};
    if (sg == 0) {  // self term
        uint4 v = *(const uint4*)(W + (size_t)node * 128 + lc * 8);
        acc8(a, v);
    }
    int e = e0 + sg;
    for (; e + 4 < e1; e += 8) {
        int s0 = esrc[e], s1 = esrc[e + 4];
        uint4 v0 = *(const uint4*)(W + (size_t)s0 * 128 + lc * 8);
        uint4 v1 = *(const uint4*)(W + (size_t)s1 * 128 + lc * 8);
        acc8(a, v0); acc8(b, v1);
    }
    if (e < e1) {
        uint4 v = *(const uint4*)(W + (size_t)esrc[e] * 128 + lc * 8);
        acc8(a, v);
    }
#pragma unroll
    for (int k = 0; k < 8; ++k) {
        a[k] += b[k];
        a[k] += __shfl_xor(a[k], 16);
        a[k] += __shfl_xor(a[k], 32);
    }
    if (lane < 16) {
        float di = dinv[node];
        int col = lane * 8;
        float o[8];
        if (col < 64) {
#pragma unroll
            for (int k = 0; k < 8; ++k) o[k] = di * a[k] + bmu[col + k];
            *(float4*)(out + (size_t)node * 64 + col) = make_float4(o[0], o[1], o[2], o[3]);
            *(float4*)(out + (size_t)node * 64 + col + 4) = make_float4(o[4], o[5], o[6], o[7]);
        } else {
#pragma unroll
            for (int k = 0; k < 8; ++k) o[k] = di * a[k] + bls[col - 64 + k];
            *(float4*)(out + (size_t)NN * 64 + (size_t)node * 64 + (col - 64)) = make_float4(o[0], o[1], o[2], o[3]);
            *(float4*)(out + (size_t)NN * 64 + (size_t)node * 64 + (col - 60)) = make_float4(o[4], o[5], o[6], o[7]);
        }
    }
}

// ---------------- GEMMs ----------------
// gemm1/gemm2: 3-buffer depth-2 pipeline with COUNTED vmcnt (T4) + raw s_barrier.
// Per K-step t: s_waitcnt vmcnt(S) lgkmcnt(0)  [tile t landed, t+1 in flight;
// lgkm(0) guarantees this wave's prior ds_reads retired before the barrier]
// -> s_barrier -> issue stage(t+2) [slot last read at t-1, all waves past it]
// -> ds_read+MFMA(t). Loads are NEVER drained to 0 inside the loop.
// LDS tile [R][8 chunks of 16B], XOR-swizzled on global source + ds_read (T2, rule #21).

#define STAGE_T(SRC, LDST, STRIDE, ROWBASE, KOFF, NCH)                                              \
    _Pragma("unroll")                                                                               \
    for (int c_ = 0; c_ < NCH; ++c_) {                                                              \
        int off_ = (c_ * 256 + t) * 16;                                                             \
        int row_ = off_ >> 7;                                                                       \
        int cc_  = (off_ >> 4) & 7;                                                                 \
        int gcb_ = ((cc_ ^ (row_ & 7)) << 4);                                                       \
        int wb_ = (c_ * 256 + (t & ~63)) * 16;                                                      \
        load_lds16((const char*)(SRC) + ((size_t)((ROWBASE) + row_) * (STRIDE) + (KOFF)) * 2 + gcb_,\
                   (char*)(LDST) + wb_);                                                            \
    }

#define COMPUTE_STEP(ACC, PA, PB)                                                                  \
    _Pragma("unroll")                                                                              \
    for (int ks = 0; ks < 2; ++ks) {                                                               \
        int sc_ = (((ks << 2) + (lane >> 4)) ^ (lane & 7)) << 3;                                   \
        s16x8 afr[4], bfr[4];                                                                      \
        _Pragma("unroll")                                                                          \
        for (int i = 0; i < 4; ++i) {                                                              \
            afr[i] = *(const s16x8*)&(PA)[(wr * 64 + i * 16 + (lane & 15)) * 64 + sc_];            \
            bfr[i] = *(const s16x8*)&(PB)[(wc * 64 + i * 16 + (lane & 15)) * 64 + sc_];            \
        }                                                                                          \
        _Pragma("unroll")                                                                          \
        for (int i = 0; i < 4; ++i)                                                                \
            _Pragma("unroll")                                                                      \
            for (int j = 0; j < 4; ++j)                                                            \
                ACC[i][j] = __builtin_amdgcn_mfma_f32_16x16x32_bf16(afr[i], bfr[j], ACC[i][j], 0, 0, 0); \
    }

#define WAIT_S10() asm volatile("s_waitcnt vmcnt(10) lgkmcnt(0)" ::: "memory")
#define WAIT_0()   asm volatile("s_waitcnt vmcnt(0) lgkmcnt(0)" ::: "memory")

// GEMM1: H1 = relu([agg1|x] @ B1 + b1) (+ x residual on cols<128). BM=64, BN=256, 3buf 120KB
__global__ __launch_bounds__(256) void gemm1_k(const __hip_bfloat16* __restrict__ A1,
                                               const __hip_bfloat16* __restrict__ B1T,
                                               const float* __restrict__ b1,
                                               __hip_bfloat16* __restrict__ H1) {
    __shared__ __hip_bfloat16 lA[3][64 * 64];
    __shared__ __hip_bfloat16 lB[3][256 * 64];
    const int bm = blockIdx.x;
    const int t = threadIdx.x, lane = t & 63;
    const int wr = 0, wc = t >> 6;
    const int r0 = bm * 64;
    f32x4 acc[4][4] = {};
#define G1_STAGE(KN, BI)  { STAGE_T(A1, lA[BI], 256, r0, (KN) * 64, 2); \
                            STAGE_T(B1T, lB[BI], 256, 0, (KN) * 64, 8); }
    G1_STAGE(0, 0);
    G1_STAGE(1, 1);
#pragma unroll
    for (int kt = 0; kt < 4; ++kt) {
        if (kt < 3) { WAIT_S10(); } else { WAIT_0(); }
        __builtin_amdgcn_s_barrier();
        if (kt + 2 < 4) { G1_STAGE(kt + 2, (kt + 2) % 3); }
        COMPUTE_STEP(acc, lA[kt % 3], lB[kt % 3]);
    }
    const int row0 = r0, col0 = wc * 64;
    unsigned short* Hs = (unsigned short*)H1;
    const unsigned short* Xb = (const unsigned short*)A1;
#pragma unroll
    for (int i = 0; i < 4; ++i)
#pragma unroll
        for (int j = 0; j < 4; ++j) {
            int col = col0 + j * 16 + (lane & 15);
#pragma unroll
            for (int r = 0; r < 4; ++r) {
                int row = row0 + i * 16 + (lane >> 4) * 4 + r;
                float v = acc[i][j][r] + b1[col];
                v = fmaxf(v, 0.0f);
                if (col < 128) v += bfu(Xb[(size_t)row * 256 + 128 + col]);
                Hs[(size_t)row * 256 + col] = fbf(v);
            }
        }
}

// GEMM2: H2 = relu(agg2@W2l + h1@W2r + b2) + (x@Wr + br). BM=64, BN=256, dual acc, 3buf
__global__ __launch_bounds__(256) void gemm2_k(const __hip_bfloat16* __restrict__ AGG2,
                                               const __hip_bfloat16* __restrict__ H1,
                                               const __hip_bfloat16* __restrict__ A1,  // x at col 128
                                               const __hip_bfloat16* __restrict__ B2T, // [256][640]
                                               const float* __restrict__ b2,
                                               const float* __restrict__ br,
                                               __hip_bfloat16* __restrict__ H2) {
    __shared__ __hip_bfloat16 lA[3][64 * 64];
    __shared__ __hip_bfloat16 lB[3][256 * 64];
    const int bm = blockIdx.x;
    const int t = threadIdx.x, lane = t & 63;
    const int wr = 0, wc = t >> 6;
    const int r0 = bm * 64;
    f32x4 accA[4][4] = {};
    f32x4 accB[4][4] = {};
#define G2_STAGE(KN, BI)  { const __hip_bfloat16* Ab_ = ((KN) < 4) ? AGG2 : (((KN) < 8) ? H1 : A1); \
                            int ko_ = ((KN) < 4) ? (KN) * 64 : (((KN) < 8) ? ((KN) - 4) * 64 : 128 + ((KN) - 8) * 64); \
                            STAGE_T(Ab_, lA[BI], 256, r0, ko_, 2); \
                            STAGE_T(B2T, lB[BI], 640, 0, (KN) * 64, 8); }
    G2_STAGE(0, 0);
    G2_STAGE(1, 1);
#pragma unroll
    for (int kt = 0; kt < 10; ++kt) {
        if (kt < 9) { WAIT_S10(); } else { WAIT_0(); }
        __builtin_amdgcn_s_barrier();
        if (kt + 2 < 10) { G2_STAGE(kt + 2, (kt + 2) % 3); }
        if (kt < 8) {
            COMPUTE_STEP(accA, lA[kt % 3], lB[kt % 3]);
        } else {
            COMPUTE_STEP(accB, lA[kt % 3], lB[kt % 3]);
        }
    }
    const int row0 = r0, col0 = wc * 64;
    unsigned short* Hs = (unsigned short*)H2;
#pragma unroll
    for (int i = 0; i < 4; ++i)
#pragma unroll
        for (int j = 0; j < 4; ++j) {
            int col = col0 + j * 16 + (lane & 15);
#pragma unroll
            for (int r = 0; r < 4; ++r) {
                int row = row0 + i * 16 + (lane >> 4) * 4 + r;
                float v = fmaxf(accA[i][j][r] + b2[col], 0.0f) + accB[i][j][r] + br[col];
                Hs[(size_t)row * 256 + col] = fbf(v);
            }
        }
}

// GEMM3: XWS = (h2 @ [Wmu|Wls]) * dinv[row]. BM=128, BN=128, waves 2x2, dbuf 64KB (R6 control)
__global__ __launch_bounds__(256) void gemm3_k(const __hip_bfloat16* __restrict__ H2,
                                               const __hip_bfloat16* __restrict__ B3T, // [128][256]
                                               const float* __restrict__ dinv,
                                               __hip_bfloat16* __restrict__ XWS) {
    __shared__ __hip_bfloat16 lA[2][128 * 64];
    __shared__ __hip_bfloat16 lB[2][128 * 64];
    const int bm = blockIdx.x;
    const int t = threadIdx.x, lane = t & 63, wid = t >> 6;
    const int wr = wid >> 1, wc = wid & 1;
    const int r0 = bm * 128;
    f32x4 acc[4][4] = {};
    STAGE_T(H2, lA[0], 256, r0, 0, 4);
    STAGE_T(B3T, lB[0], 256, 0, 0, 4);
    __syncthreads();
    int cur = 0;
    for (int kt = 0; kt < 4; ++kt) {
        if (kt < 3) {
            STAGE_T(H2, lA[cur ^ 1], 256, r0, (kt + 1) * 64, 4);
            STAGE_T(B3T, lB[cur ^ 1], 256, 0, (kt + 1) * 64, 4);
        }
        COMPUTE_STEP(acc, lA[cur], lB[cur]);
        __syncthreads();
        cur ^= 1;
    }
    const int row0 = r0 + wr * 64, col0 = wc * 64;
    unsigned short* Ws = (unsigned short*)XWS;
#pragma unroll
    for (int i = 0; i < 4; ++i)
#pragma unroll
        for (int j = 0; j < 4; ++j) {
            int col = col0 + j * 16 + (lane & 15);
#pragma unroll
            for (int r = 0; r < 4; ++r) {
                int row = row0 + i * 16 + (lane >> 4) * 4 + r;
                float di = (row < NN) ? dinv[row] : 0.0f;
                Ws[(size_t)row * 128 + col] = fbf(acc[i][j][r] * di);
            }
        }
}

// ---------------- launch ----------------

extern "C" void kernel_launch(void* const* d_in, const int* in_sizes, int n_in,
                              void* d_out, int out_size, void* d_ws, size_t ws_size,
                              hipStream_t stream) {
    const float* x   = (const float*)d_in[0];
    const int*   ei  = (const int*)d_in[1];
    const float* W1l = (const float*)d_in[2];
    const float* W1r = (const float*)d_in[3];
    const float* b1  = (const float*)d_in[4];
    const float* W2l = (const float*)d_in[5];
    const float* W2r = (const float*)d_in[6];
    const float* b2  = (const float*)d_in[7];
    const float* Wr  = (const float*)d_in[8];
    const float* br  = (const float*)d_in[9];
    const float* Wmu = (const float*)d_in[10];
    const float* bmu = (const float*)d_in[11];
    const float* Wls = (const float*)d_in[12];
    const float* bls = (const float*)d_in[13];
    float* out = (float*)d_out;

    char* w = (char*)d_ws;
    size_t o = 0;
    int* counts = (int*)(w + o);           o += 400128;
    int* rp     = (int*)(w + o);           o += 400128;
    int* bsum   = (int*)(w + o);           o += 1024;
    int* esrc   = (int*)(w + o);           o += 3200000;
    float* dinv = (float*)(w + o);         o += 400128;
    unsigned short* B1T = (unsigned short*)(w + o); o += 131072;
    unsigned short* B2T = (unsigned short*)(w + o); o += 327680;
    unsigned short* B3T = (unsigned short*)(w + o); o += 65536;
    __hip_bfloat16* A1   = (__hip_bfloat16*)(w + o); o += (size_t)MPAD * 256 * 2;  // [agg1|x]
    __hip_bfloat16* H1   = (__hip_bfloat16*)(w + o); o += (size_t)MPAD * 256 * 2;
    __hip_bfloat16* AGG2 = (__hip_bfloat16*)(w + o); o += (size_t)MPAD * 256 * 2;  // reused as XWS
    __hip_bfloat16* H2   = (__hip_bfloat16*)(w + o); o += (size_t)MPAD * 256 * 2;
    __hip_bfloat16* XWS  = AGG2;
    (void)ws_size; (void)in_sizes; (void)n_in; (void)out_size;

    hipMemsetAsync(counts, 0, NN * 4, stream);

    hist_k<<<EE / 256, 256, 0, stream>>>(ei, counts);
    scan1_k<<<98, 256, 0, stream>>>(counts, rp, bsum);
    scan2_k<<<1, 64, 0, stream>>>(bsum, 98);
    scan3_k<<<391, 256, 0, stream>>>(rp, bsum, counts, dinv);
    fill_k<<<EE / 256, 256, 0, stream>>>(ei, counts, esrc);

    xcvt_k<<<NN * 32 / 256, 256, 0, stream>>>(x, A1);
    wprep_k<<<1024, 256, 0, stream>>>(W1l, W1r, W2l, W2r, Wr, Wmu, Wls, B1T, B2T, B3T);

    agg1_k<<<NN / 4, 256, 0, stream>>>(rp, esrc, A1);
    gemm1_k<<<MT64, 256, 0, stream>>>(A1, (const __hip_bfloat16*)B1T, b1, H1);
    agg2_k<<<NN / 4, 256, 0, stream>>>(rp, esrc, H1, AGG2);
    gemm2_k<<<MT64, 256, 0, stream>>>(AGG2, H1, A1, (const __hip_bfloat16*)B2T, b2, br, H2);
    gemm3_k<<<MT128, 256, 0, stream>>>(H2, (const __hip_bfloat16*)B3T, dinv, XWS);
    gcnagg_k<<<NN / 4, 256, 0, stream>>>(rp, esrc, XWS, dinv, bmu, bls, out);
}

// Round 8
// 505.880 us; speedup vs baseline: 1.1238x; 1.1238x over previous
//
#include <hip/hip_runtime.h>
#include <hip/hip_bf16.h>

#define NN 100000
#define EE 800000
#define MPAD 100096   // 782*128 = 1564*64 = 391*256
#define MT64 1564
#define MT128 782

typedef __attribute__((ext_vector_type(4))) float f32x4;
typedef __attribute__((ext_vector_type(8))) short s16x8;

__device__ __forceinline__ float bfu(unsigned short u) {
    union { unsigned i; float f; } x; x.i = ((unsigned)u) << 16; return x.f;
}
__device__ __forceinline__ unsigned short fbf(float f) {
    union { float f; unsigned i; } x; x.f = f;
    unsigned r = x.i + (((x.i >> 16) & 1u) + 0x7fffu);  // RNE
    return (unsigned short)(r >> 16);
}
__device__ __forceinline__ uint4 pack8(const float* a) {
    uint4 o;
    o.x = (unsigned)fbf(a[0]) | ((unsigned)fbf(a[1]) << 16);
    o.y = (unsigned)fbf(a[2]) | ((unsigned)fbf(a[3]) << 16);
    o.z = (unsigned)fbf(a[4]) | ((unsigned)fbf(a[5]) << 16);
    o.w = (unsigned)fbf(a[6]) | ((unsigned)fbf(a[7]) << 16);
    return o;
}
__device__ __forceinline__ void acc8(float* a, uint4 v) {
    a[0] += bfu((unsigned short)v.x); a[1] += bfu((unsigned short)(v.x >> 16));
    a[2] += bfu((unsigned short)v.y); a[3] += bfu((unsigned short)(v.y >> 16));
    a[4] += bfu((unsigned short)v.z); a[5] += bfu((unsigned short)(v.z >> 16));
    a[6] += bfu((unsigned short)v.w); a[7] += bfu((unsigned short)(v.w >> 16));
}
__device__ __forceinline__ void load_lds16(const void* g, void* l) {
    __builtin_amdgcn_global_load_lds((const __attribute__((address_space(1))) void*)g,
                                     (__attribute__((address_space(3))) void*)l, 16, 0, 0);
}

// ---------------- graph prep ----------------

__global__ void hist_k(const int* __restrict__ ei, int* __restrict__ counts) {
    int e = blockIdx.x * 256 + threadIdx.x;
    if (e < EE) atomicAdd(&counts[ei[EE + e]], 1);
}

__global__ void scan1_k(const int* __restrict__ counts, int* __restrict__ rp, int* __restrict__ bsum) {
    __shared__ int lds[256];
    int b = blockIdx.x, t = threadIdx.x;
    int base = b * 1024 + t * 4;
    int v[4]; int s = 0;
#pragma unroll
    for (int j = 0; j < 4; ++j) { v[j] = (base + j < NN) ? counts[base + j] : 0; s += v[j]; }
    lds[t] = s; __syncthreads();
    for (int off = 1; off < 256; off <<= 1) {
        int x = (t >= off) ? lds[t - off] : 0;
        __syncthreads();
        lds[t] += x;
        __syncthreads();
    }
    int run = lds[t] - s;
    if (t == 255) bsum[b] = lds[255];
#pragma unroll
    for (int j = 0; j < 4; ++j) { if (base + j < NN) rp[base + j] = run; run += v[j]; }
}

// one-wave shuffle prefix over nb<=128 block sums
__global__ void scan2_k(int* __restrict__ bsum, int nb) {
    int l = threadIdx.x;
    int v0 = (l < nb) ? bsum[l] : 0;
    int v1 = (64 + l < nb) ? bsum[64 + l] : 0;
    int s0 = v0, s1 = v1;
    for (int off = 1; off < 64; off <<= 1) {
        int t0 = __shfl_up(s0, off); if (l >= off) s0 += t0;
        int t1 = __shfl_up(s1, off); if (l >= off) s1 += t1;
    }
    int tot0 = __shfl(s0, 63);
    if (l < nb) bsum[l] = s0 - v0;
    if (64 + l < nb) bsum[64 + l] = tot0 + s1 - v1;
}

// finalize row_ptr, make fill copy (into counts), dinv = rsqrt(deg+1)
__global__ void scan3_k(int* __restrict__ rp, const int* __restrict__ bsum,
                        int* __restrict__ counts, float* __restrict__ dinv) {
    int i = blockIdx.x * 256 + threadIdx.x;
    if (i == 0) rp[NN] = EE;
    if (i < NN) {
        int v = rp[i] + bsum[i >> 10];
        int deg = counts[i];
        rp[i] = v;
        counts[i] = v;  // fill cursor
        dinv[i] = rsqrtf((float)deg + 1.0f);
    }
}

__global__ void fill_k(const int* __restrict__ ei, int* __restrict__ fill, int* __restrict__ esrc) {
    int e = blockIdx.x * 256 + threadIdx.x;
    if (e < EE) {
        int d = ei[EE + e];
        int slot = atomicAdd(&fill[d], 1);
        esrc[slot] = ei[e];
    }
}

// ---------------- conversions ----------------

__global__ void xcvt_k(const float* __restrict__ x, __hip_bfloat16* __restrict__ A1) {
    int idx = blockIdx.x * 256 + threadIdx.x;
    if (idx < NN * 32) {
        int row = idx >> 5; int c4 = (idx & 31) * 4;
        float4 v = *(const float4*)(x + (size_t)row * 128 + c4);
        ushort4 o; o.x = fbf(v.x); o.y = fbf(v.y); o.z = fbf(v.z); o.w = fbf(v.w);
        *(ushort4*)((unsigned short*)A1 + (size_t)row * 256 + 128 + c4) = o;
    }
}

// weights -> bf16 in MFMA FRAGMENT order: chunk per (wc,kt,ks,j) = 64 lanes x 8 bf16 (1KB),
// element = B[k = kt*64+ks*32+(lane>>4)*8+e][col = wc*64+j*16+(lane&15)].
// A wave's bfr[j] load is then ONE coalesced 16B/lane global load; B stays L2-resident.
__global__ void wprep_k(const float* __restrict__ W1l, const float* __restrict__ W1r,
                        const float* __restrict__ W2l, const float* __restrict__ W2r,
                        const float* __restrict__ Wr,  const float* __restrict__ Wmu,
                        const float* __restrict__ Wls,
                        unsigned short* __restrict__ B1F, unsigned short* __restrict__ B2F,
                        unsigned short* __restrict__ B3F) {
    int idx = blockIdx.x * 256 + threadIdx.x;
    if (idx < 65536) {                         // B1F: wc4 kt4 ks2 j4 lane64 e8
        int t = idx;
        int e = t & 7; t >>= 3;
        int lane = t & 63; t >>= 6;
        int j = t & 3; t >>= 2;
        int ks = t & 1; t >>= 1;
        int kt = t & 3; t >>= 2;
        int wc = t;
        int col = wc * 64 + j * 16 + (lane & 15);
        int k = kt * 64 + ks * 32 + (lane >> 4) * 8 + e;
        float v = (k < 128) ? W1l[k * 256 + col] : W1r[(k - 128) * 256 + col];
        B1F[idx] = fbf(v);
    } else if (idx < 229376) {                 // B2F: wc4 kt10 ks2 j4 lane64 e8
        int t = idx - 65536;
        int o = t;
        int e = t & 7; t >>= 3;
        int lane = t & 63; t >>= 6;
        int j = t & 3; t >>= 2;
        int ks = t & 1; t >>= 1;
        int kt = t % 10;
        int wc = t / 10;
        int col = wc * 64 + j * 16 + (lane & 15);
        int k = kt * 64 + ks * 32 + (lane >> 4) * 8 + e;
        float v = (k < 256) ? W2l[k * 256 + col]
                : (k < 512) ? W2r[(k - 256) * 256 + col]
                            : Wr[(k - 512) * 256 + col];
        B2F[o] = fbf(v);
        (void)e;
    } else if (idx < 262144) {                 // B3F: wc2 kt4 ks2 j4 lane64 e8
        int t = idx - 229376;
        int o = t;
        int e = t & 7; t >>= 3;
        int lane = t & 63; t >>= 6;
        int j = t & 3; t >>= 2;
        int ks = t & 1; t >>= 1;
        int kt = t & 3; t >>= 2;
        int wc = t;
        int col = wc * 64 + j * 16 + (lane & 15);
        int k = kt * 64 + ks * 32 + (lane >> 4) * 8 + e;
        float v = (col < 64) ? Wmu[k * 64 + col] : Wls[k * 64 + (col - 64)];
        B3F[o] = fbf(v);
    }
}

// ---------------- aggregations (wave per node, multi-edge subgroups, 2x unroll) ----------------

__global__ __launch_bounds__(256) void agg1_k(const int* __restrict__ rp, const int* __restrict__ esrc,
                                              __hip_bfloat16* __restrict__ A1) {
    int wid = threadIdx.x >> 6, lane = threadIdx.x & 63;
    int node = blockIdx.x * 4 + wid;
    if (node >= NN) return;
    int e0 = rp[node], e1 = rp[node + 1];
    int sg = lane >> 4, lc = lane & 15;
    const unsigned short* X = (const unsigned short*)A1;
    float a[8] = {}, b[8] = {};
    int e = e0 + sg;
    for (; e + 4 < e1; e += 8) {
        int s0 = esrc[e], s1 = esrc[e + 4];
        uint4 v0 = *(const uint4*)(X + (size_t)s0 * 256 + 128 + lc * 8);
        uint4 v1 = *(const uint4*)(X + (size_t)s1 * 256 + 128 + lc * 8);
        acc8(a, v0); acc8(b, v1);
    }
    if (e < e1) {
        uint4 v = *(const uint4*)(X + (size_t)esrc[e] * 256 + 128 + lc * 8);
        acc8(a, v);
    }
#pragma unroll
    for (int k = 0; k < 8; ++k) {
        a[k] += b[k];
        a[k] += __shfl_xor(a[k], 16);
        a[k] += __shfl_xor(a[k], 32);
    }
    int deg = e1 - e0;
    float sc = 1.0f / (float)(deg > 1 ? deg : 1);
    if (lane < 16) {
#pragma unroll
        for (int k = 0; k < 8; ++k) a[k] *= sc;
        *(uint4*)((unsigned short*)A1 + (size_t)node * 256 + lane * 8) = pack8(a);
    }
}

__global__ __launch_bounds__(256) void agg2_k(const int* __restrict__ rp, const int* __restrict__ esrc,
                                              const __hip_bfloat16* __restrict__ H1,
                                              __hip_bfloat16* __restrict__ AGG2) {
    int wid = threadIdx.x >> 6, lane = threadIdx.x & 63;
    int node = blockIdx.x * 4 + wid;
    if (node >= NN) return;
    int e0 = rp[node], e1 = rp[node + 1];
    int sg = lane >> 5, lc = lane & 31;
    const unsigned short* H = (const unsigned short*)H1;
    float a[8] = {}, b[8] = {};
    int e = e0 + sg;
    for (; e + 2 < e1; e += 4) {
        int s0 = esrc[e], s1 = esrc[e + 2];
        uint4 v0 = *(const uint4*)(H + (size_t)s0 * 256 + lc * 8);
        uint4 v1 = *(const uint4*)(H + (size_t)s1 * 256 + lc * 8);
        acc8(a, v0); acc8(b, v1);
    }
    if (e < e1) {
        uint4 v = *(const uint4*)(H + (size_t)esrc[e] * 256 + lc * 8);
        acc8(a, v);
    }
#pragma unroll
    for (int k = 0; k < 8; ++k) {
        a[k] += b[k];
        a[k] += __shfl_xor(a[k], 32);
    }
    int deg = e1 - e0;
    float sc = 1.0f / (float)(deg > 1 ? deg : 1);
    if (lane < 32) {
#pragma unroll
        for (int k = 0; k < 8; ++k) a[k] *= sc;
        *(uint4*)((unsigned short*)AGG2 + (size_t)node * 256 + lane * 8) = pack8(a);
    }
}

__global__ __launch_bounds__(256) void gcnagg_k(const int* __restrict__ rp, const int* __restrict__ esrc,
                                                const __hip_bfloat16* __restrict__ XWS,
                                                const float* __restrict__ dinv,
                                                const float* __restrict__ bmu, const float* __restrict__ bls,
                                                float* __restrict__ out) {
    int wid = threadIdx.x >> 6, lane = threadIdx.x & 63;
    int node = blockIdx.x * 4 + wid;
    if (node >= NN) return;
    int e0 = rp[node], e1 = rp[node + 1];
    int sg = lane >> 4, lc = lane & 15;
    const unsigned short* W = (const unsigned short*)XWS;
    float a[8] = {}, b[8] = {};
    if (sg == 0) {  // self term
        uint4 v = *(const uint4*)(W + (size_t)node * 128 + lc * 8);
        acc8(a, v);
    }
    int e = e0 + sg;
    for (; e + 4 < e1; e += 8) {
        int s0 = esrc[e], s1 = esrc[e + 4];
        uint4 v0 = *(const uint4*)(W + (size_t)s0 * 128 + lc * 8);
        uint4 v1 = *(const uint4*)(W + (size_t)s1 * 128 + lc * 8);
        acc8(a, v0); acc8(b, v1);
    }
    if (e < e1) {
        uint4 v = *(const uint4*)(W + (size_t)esrc[e] * 128 + lc * 8);
        acc8(a, v);
    }
#pragma unroll
    for (int k = 0; k < 8; ++k) {
        a[k] += b[k];
        a[k] += __shfl_xor(a[k], 16);
        a[k] += __shfl_xor(a[k], 32);
    }
    if (lane < 16) {
        float di = dinv[node];
        int col = lane * 8;
        float o[8];
        if (col < 64) {
#pragma unroll
            for (int k = 0; k < 8; ++k) o[k] = di * a[k] + bmu[col + k];
            *(float4*)(out + (size_t)node * 64 + col) = make_float4(o[0], o[1], o[2], o[3]);
            *(float4*)(out + (size_t)node * 64 + col + 4) = make_float4(o[4], o[5], o[6], o[7]);
        } else {
#pragma unroll
            for (int k = 0; k < 8; ++k) o[k] = di * a[k] + bls[col - 64 + k];
            *(float4*)(out + (size_t)NN * 64 + (size_t)node * 64 + (col - 64)) = make_float4(o[0], o[1], o[2], o[3]);
            *(float4*)(out + (size_t)NN * 64 + (size_t)node * 64 + (col - 60)) = make_float4(o[4], o[5], o[6], o[7]);
        }
    }
}

// ---------------- GEMMs: A-only LDS (dbuf, depth-1), B global->reg from L2 fragments ----------
// LDS A tile [R][8 chunks of 16B], XOR-swizzled source + read (T2). B loads are plain
// coalesced 16B/lane global loads from the fragment-ordered BxF arrays (L2-resident);
// the compiler schedules their waitcnt across MFMAs — no barrier involvement.

#define STAGE_T(SRC, LDST, STRIDE, ROWBASE, KOFF, NCH)                                              \
    _Pragma("unroll")                                                                               \
    for (int c_ = 0; c_ < NCH; ++c_) {                                                              \
        int off_ = (c_ * 256 + t) * 16;                                                             \
        int row_ = off_ >> 7;                                                                       \
        int cc_  = (off_ >> 4) & 7;                                                                 \
        int gcb_ = ((cc_ ^ (row_ & 7)) << 4);                                                       \
        int wb_ = (c_ * 256 + (t & ~63)) * 16;                                                      \
        load_lds16((const char*)(SRC) + ((size_t)((ROWBASE) + row_) * (STRIDE) + (KOFF)) * 2 + gcb_,\
                   (char*)(LDST) + wb_);                                                            \
    }

#define COMPUTE_GB(ACC, PA, BF, KT, NKT, WRBASE)                                                   \
    _Pragma("unroll")                                                                              \
    for (int ks = 0; ks < 2; ++ks) {                                                               \
        int sc_ = (((ks << 2) + (lane >> 4)) ^ (lane & 7)) << 3;                                   \
        s16x8 afr[4], bfr[4];                                                                      \
        _Pragma("unroll")                                                                          \
        for (int j = 0; j < 4; ++j)                                                                \
            bfr[j] = *(const s16x8*)((BF) + (size_t)((((((wc) * (NKT) + (KT)) * 2 + ks) * 4 + j) * 64 + lane) << 3)); \
        _Pragma("unroll")                                                                          \
        for (int i = 0; i < 4; ++i)                                                                \
            afr[i] = *(const s16x8*)&(PA)[((WRBASE) + i * 16 + (lane & 15)) * 64 + sc_];           \
        _Pragma("unroll")                                                                          \
        for (int i = 0; i < 4; ++i)                                                                \
            _Pragma("unroll")                                                                      \
            for (int j = 0; j < 4; ++j)                                                            \
                ACC[i][j] = __builtin_amdgcn_mfma_f32_16x16x32_bf16(afr[i], bfr[j], ACC[i][j], 0, 0, 0); \
    }

// GEMM1: H1 = relu([agg1|x] @ B1 + b1) (+ x residual on cols<128). BM=64, BN=256, LDS 16KB
__global__ __launch_bounds__(256) void gemm1_k(const __hip_bfloat16* __restrict__ A1,
                                               const unsigned short* __restrict__ B1F,
                                               const float* __restrict__ b1,
                                               __hip_bfloat16* __restrict__ H1) {
    __shared__ __hip_bfloat16 lA[2][64 * 64];
    const int bm = blockIdx.x;
    const int t = threadIdx.x, lane = t & 63;
    const int wc = t >> 6;
    const int r0 = bm * 64;
    f32x4 acc[4][4] = {};
    STAGE_T(A1, lA[0], 256, r0, 0, 2);
    __syncthreads();
    int cur = 0;
#pragma unroll
    for (int kt = 0; kt < 4; ++kt) {
        if (kt < 3) { STAGE_T(A1, lA[cur ^ 1], 256, r0, (kt + 1) * 64, 2); }
        COMPUTE_GB(acc, lA[cur], B1F, kt, 4, 0);
        __syncthreads();
        cur ^= 1;
    }
    const int row0 = r0, col0 = wc * 64;
    unsigned short* Hs = (unsigned short*)H1;
    const unsigned short* Xb = (const unsigned short*)A1;
#pragma unroll
    for (int i = 0; i < 4; ++i)
#pragma unroll
        for (int j = 0; j < 4; ++j) {
            int col = col0 + j * 16 + (lane & 15);
#pragma unroll
            for (int r = 0; r < 4; ++r) {
                int row = row0 + i * 16 + (lane >> 4) * 4 + r;
                float v = acc[i][j][r] + b1[col];
                v = fmaxf(v, 0.0f);
                if (col < 128) v += bfu(Xb[(size_t)row * 256 + 128 + col]);
                Hs[(size_t)row * 256 + col] = fbf(v);
            }
        }
}

// GEMM2: H2 = relu(agg2@W2l + h1@W2r + b2) + (x@Wr + br). BM=64, BN=256, dual acc, LDS 16KB
__global__ __launch_bounds__(256) void gemm2_k(const __hip_bfloat16* __restrict__ AGG2,
                                               const __hip_bfloat16* __restrict__ H1,
                                               const __hip_bfloat16* __restrict__ A1,  // x at col 128
                                               const unsigned short* __restrict__ B2F,
                                               const float* __restrict__ b2,
                                               const float* __restrict__ br,
                                               __hip_bfloat16* __restrict__ H2) {
    __shared__ __hip_bfloat16 lA[2][64 * 64];
    const int bm = blockIdx.x;
    const int t = threadIdx.x, lane = t & 63;
    const int wc = t >> 6;
    const int r0 = bm * 64;
    f32x4 accA[4][4] = {};
    f32x4 accB[4][4] = {};
    STAGE_T(AGG2, lA[0], 256, r0, 0, 2);
    __syncthreads();
    int cur = 0;
#pragma unroll
    for (int kt = 0; kt < 10; ++kt) {
        if (kt < 9) {
            int kn = kt + 1;
            const __hip_bfloat16* Ab = (kn < 4) ? AGG2 : (kn < 8 ? H1 : A1);
            int ko = (kn < 4) ? kn * 64 : (kn < 8 ? (kn - 4) * 64 : 128 + (kn - 8) * 64);
            STAGE_T(Ab, lA[cur ^ 1], 256, r0, ko, 2);
        }
        if (kt < 8) {
            COMPUTE_GB(accA, lA[cur], B2F, kt, 10, 0);
        } else {
            COMPUTE_GB(accB, lA[cur], B2F, kt, 10, 0);
        }
        __syncthreads();
        cur ^= 1;
    }
    const int row0 = r0, col0 = wc * 64;
    unsigned short* Hs = (unsigned short*)H2;
#pragma unroll
    for (int i = 0; i < 4; ++i)
#pragma unroll
        for (int j = 0; j < 4; ++j) {
            int col = col0 + j * 16 + (lane & 15);
#pragma unroll
            for (int r = 0; r < 4; ++r) {
                int row = row0 + i * 16 + (lane >> 4) * 4 + r;
                float v = fmaxf(accA[i][j][r] + b2[col], 0.0f) + accB[i][j][r] + br[col];
                Hs[(size_t)row * 256 + col] = fbf(v);
            }
        }
}

// GEMM3: XWS = (h2 @ [Wmu|Wls]) * dinv[row]. BM=128, BN=128, waves 2x2, LDS 32KB
__global__ __launch_bounds__(256) void gemm3_k(const __hip_bfloat16* __restrict__ H2,
                                               const unsigned short* __restrict__ B3F,
                                               const float* __restrict__ dinv,
                                               __hip_bfloat16* __restrict__ XWS) {
    __shared__ __hip_bfloat16 lA[2][128 * 64];
    const int bm = blockIdx.x;
    const int t = threadIdx.x, lane = t & 63, wid = t >> 6;
    const int wr = wid >> 1, wc = wid & 1;
    const int r0 = bm * 128;
    f32x4 acc[4][4] = {};
    STAGE_T(H2, lA[0], 256, r0, 0, 4);
    __syncthreads();
    int cur = 0;
#pragma unroll
    for (int kt = 0; kt < 4; ++kt) {
        if (kt < 3) { STAGE_T(H2, lA[cur ^ 1], 256, r0, (kt + 1) * 64, 4); }
        COMPUTE_GB(acc, lA[cur], B3F, kt, 4, wr * 64);
        __syncthreads();
        cur ^= 1;
    }
    const int row0 = r0 + wr * 64, col0 = wc * 64;
    unsigned short* Ws = (unsigned short*)XWS;
#pragma unroll
    for (int i = 0; i < 4; ++i)
#pragma unroll
        for (int j = 0; j < 4; ++j) {
            int col = col0 + j * 16 + (lane & 15);
#pragma unroll
            for (int r = 0; r < 4; ++r) {
                int row = row0 + i * 16 + (lane >> 4) * 4 + r;
                float di = (row < NN) ? dinv[row] : 0.0f;
                Ws[(size_t)row * 128 + col] = fbf(acc[i][j][r] * di);
            }
        }
}

// ---------------- launch ----------------

extern "C" void kernel_launch(void* const* d_in, const int* in_sizes, int n_in,
                              void* d_out, int out_size, void* d_ws, size_t ws_size,
                              hipStream_t stream) {
    const float* x   = (const float*)d_in[0];
    const int*   ei  = (const int*)d_in[1];
    const float* W1l = (const float*)d_in[2];
    const float* W1r = (const float*)d_in[3];
    const float* b1  = (const float*)d_in[4];
    const float* W2l = (const float*)d_in[5];
    const float* W2r = (const float*)d_in[6];
    const float* b2  = (const float*)d_in[7];
    const float* Wr  = (const float*)d_in[8];
    const float* br  = (const float*)d_in[9];
    const float* Wmu = (const float*)d_in[10];
    const float* bmu = (const float*)d_in[11];
    const float* Wls = (const float*)d_in[12];
    const float* bls = (const float*)d_in[13];
    float* out = (float*)d_out;

    char* w = (char*)d_ws;
    size_t o = 0;
    int* counts = (int*)(w + o);           o += 400128;
    int* rp     = (int*)(w + o);           o += 400128;
    int* bsum   = (int*)(w + o);           o += 1024;
    int* esrc   = (int*)(w + o);           o += 3200000;
    float* dinv = (float*)(w + o);         o += 400128;
    unsigned short* B1F = (unsigned short*)(w + o); o += 131072;
    unsigned short* B2F = (unsigned short*)(w + o); o += 327680;
    unsigned short* B3F = (unsigned short*)(w + o); o += 65536;
    __hip_bfloat16* A1   = (__hip_bfloat16*)(w + o); o += (size_t)MPAD * 256 * 2;  // [agg1|x]
    __hip_bfloat16* H1   = (__hip_bfloat16*)(w + o); o += (size_t)MPAD * 256 * 2;
    __hip_bfloat16* AGG2 = (__hip_bfloat16*)(w + o); o += (size_t)MPAD * 256 * 2;  // reused as XWS
    __hip_bfloat16* H2   = (__hip_bfloat16*)(w + o); o += (size_t)MPAD * 256 * 2;
    __hip_bfloat16* XWS  = AGG2;
    (void)ws_size; (void)in_sizes; (void)n_in; (void)out_size;

    hipMemsetAsync(counts, 0, NN * 4, stream);

    hist_k<<<EE / 256, 256, 0, stream>>>(ei, counts);
    scan1_k<<<98, 256, 0, stream>>>(counts, rp, bsum);
    scan2_k<<<1, 64, 0, stream>>>(bsum, 98);
    scan3_k<<<391, 256, 0, stream>>>(rp, bsum, counts, dinv);
    fill_k<<<EE / 256, 256, 0, stream>>>(ei, counts, esrc);

    xcvt_k<<<NN * 32 / 256, 256, 0, stream>>>(x, A1);
    wprep_k<<<1024, 256, 0, stream>>>(W1l, W1r, W2l, W2r, Wr, Wmu, Wls, B1F, B2F, B3F);

    agg1_k<<<NN / 4, 256, 0, stream>>>(rp, esrc, A1);
    gemm1_k<<<MT64, 256, 0, stream>>>(A1, B1F, b1, H1);
    agg2_k<<<NN / 4, 256, 0, stream>>>(rp, esrc, H1, AGG2);
    gemm2_k<<<MT64, 256, 0, stream>>>(AGG2, H1, A1, B2F, b2, br, H2);
    gemm3_k<<<MT128, 256, 0, stream>>>(H2, B3F, dinv, XWS);
    gcnagg_k<<<NN / 4, 256, 0, stream>>>(rp, esrc, XWS, dinv, bmu, bls, out);
}